// Round 4
// baseline (496.332 us; speedup 1.0000x reference)
//
#include <hip/hip_runtime.h>
#include <hip/hip_bf16.h>

#define THREADS 256

// ---------------- helpers ----------------

__device__ inline unsigned short f2bf(float f) {  // round-to-nearest-even
    unsigned int u = __float_as_uint(f);
    unsigned int r = (u + 0x7fffu + ((u >> 16) & 1u)) >> 16;
    return (unsigned short)r;
}

__device__ inline unsigned int pack_bf2(float x, float y) {
    return (unsigned int)f2bf(x) | ((unsigned int)f2bf(y) << 16);
}

__device__ inline float2 bf2_to_f2(unsigned int u) {  // low bf16 -> x, high bf16 -> y
    float2 r;
    r.x = __uint_as_float(u << 16);
    r.y = __uint_as_float(u & 0xffff0000u);
    return r;
}

// ---------------- CSR build ----------------

__global__ void k_zero_i(int* p, int n) {
    int i = blockIdx.x * THREADS + threadIdx.x;
    if (i < n) p[i] = 0;
}

__global__ void k_hist(const int* __restrict__ dst, int* __restrict__ cnt, int E) {
    int e = blockIdx.x * THREADS + threadIdx.x;
    if (e < E) atomicAdd(&cnt[dst[e]], 1);
}

// per-block scan of 1024 ints (4/thread), exclusive within block; bsum gets block
// total; also emits dinv[i] = rsqrt(cnt[i]+1)  (+1 = self-loop)
__global__ __launch_bounds__(256) void k_scan1(const int* __restrict__ cnt, int* __restrict__ part,
                                               int* __restrict__ bsum, float* __restrict__ dinv,
                                               int n) {
    __shared__ int s[256];
    int t = threadIdx.x;
    int base = blockIdx.x * 1024 + t * 4;
    int4 v = make_int4(0, 0, 0, 0);
    if (base + 3 < n) v = *(const int4*)(cnt + base);
    else {
        if (base < n) v.x = cnt[base];
        if (base + 1 < n) v.y = cnt[base + 1];
        if (base + 2 < n) v.z = cnt[base + 2];
        if (base + 3 < n) v.w = cnt[base + 3];
    }
    if (base + 3 < n) {
        float4 dv;
        dv.x = rsqrtf((float)v.x + 1.0f);
        dv.y = rsqrtf((float)v.y + 1.0f);
        dv.z = rsqrtf((float)v.z + 1.0f);
        dv.w = rsqrtf((float)v.w + 1.0f);
        *(float4*)(dinv + base) = dv;
    } else {
        if (base < n) dinv[base] = rsqrtf((float)v.x + 1.0f);
        if (base + 1 < n) dinv[base + 1] = rsqrtf((float)v.y + 1.0f);
        if (base + 2 < n) dinv[base + 2] = rsqrtf((float)v.z + 1.0f);
        if (base + 3 < n) dinv[base + 3] = rsqrtf((float)v.w + 1.0f);
    }
    int mysum = v.x + v.y + v.z + v.w;
    s[t] = mysum;
    __syncthreads();
    for (int off = 1; off < 256; off <<= 1) {
        int add = (t >= off) ? s[t - off] : 0;
        __syncthreads();
        s[t] += add;
        __syncthreads();
    }
    int excl = s[t] - mysum;
    if (base < n) part[base] = excl;
    if (base + 1 < n) part[base + 1] = excl + v.x;
    if (base + 2 < n) part[base + 2] = excl + v.x + v.y;
    if (base + 3 < n) part[base + 3] = excl + v.x + v.y + v.z;
    if (t == 255) bsum[blockIdx.x] = s[255];
}

__global__ void k_scan2(int* bsum, int nblk) {
    __shared__ int s[128];
    int t = threadIdx.x;
    int v = (t < nblk) ? bsum[t] : 0;
    s[t] = v;
    __syncthreads();
    for (int off = 1; off < 128; off <<= 1) {
        int add = (t >= off) ? s[t - off] : 0;
        __syncthreads();
        s[t] += add;
        __syncthreads();
    }
    if (t < nblk) bsum[t] = s[t] - v;  // exclusive
}

__global__ void k_addoff(int* __restrict__ rp, const int* __restrict__ bsum,
                         int* __restrict__ cursor, int n, int E) {
    int i = blockIdx.x * THREADS + threadIdx.x;
    if (i < n) {
        int v = rp[i] + bsum[i >> 10];
        rp[i] = v;
        cursor[i] = v;
    } else if (i == n) {
        rp[n] = E;
    }
}

// place each edge's src into its dst bucket (4 B/edge — weights folded into h')
__global__ void k_permute(const int* __restrict__ src, const int* __restrict__ dst,
                          int* __restrict__ cursor, int* __restrict__ eperm, int E) {
    int e = blockIdx.x * THREADS + threadIdx.x;
    if (e >= E) return;
    int d = dst[e];
    int pos = atomicAdd(&cursor[d], 1);
    eperm[pos] = src[e];
}

// ---------------- GEMM: C[M x N](bf16) = dinv[row] * (A[M x 128] @ W[128 x N]) --------
// ABF16_RELU: A is bf16 and relu is applied on load (layer 2). Else A fp32 (layer 1).

template <bool ABF16_RELU>
__global__ __launch_bounds__(256) void k_gemm(const void* __restrict__ Av,
                                              const float* __restrict__ W,
                                              const float* __restrict__ dinv,
                                              unsigned short* __restrict__ C, int M, int N) {
    __shared__ float As[32][68];
    __shared__ float Ws[32][68];
    const int t = threadIdx.x;
    const int m0 = blockIdx.x * 64;
    const int bn0 = blockIdx.y * 64;
    const int tm = t & 15;
    const int tn = t >> 4;
    float acc[4][4] = {};

    for (int kk = 0; kk < 128; kk += 32) {
        if (ABF16_RELU) {   // A tile 64x32 bf16 -> relu -> transposed
            const unsigned short* A = (const unsigned short*)Av;
            int r = t >> 2;            // 0..63
            int c = (t & 3) * 8;       // 0,8,16,24
            int row = m0 + r;
            uint4 u = make_uint4(0, 0, 0, 0);
            if (row < M) u = *(const uint4*)(A + (size_t)row * 128 + kk + c);
            float2 f0 = bf2_to_f2(u.x), f1 = bf2_to_f2(u.y);
            float2 f2v = bf2_to_f2(u.z), f3 = bf2_to_f2(u.w);
            As[c + 0][r] = fmaxf(f0.x, 0.f);
            As[c + 1][r] = fmaxf(f0.y, 0.f);
            As[c + 2][r] = fmaxf(f1.x, 0.f);
            As[c + 3][r] = fmaxf(f1.y, 0.f);
            As[c + 4][r] = fmaxf(f2v.x, 0.f);
            As[c + 5][r] = fmaxf(f2v.y, 0.f);
            As[c + 6][r] = fmaxf(f3.x, 0.f);
            As[c + 7][r] = fmaxf(f3.y, 0.f);
        } else {            // A tile 64x32 fp32 -> transposed
            const float* A = (const float*)Av;
            int r = t >> 3;            // 0..31
            int c = (t & 7) * 4;       // 0,4,..,28
#pragma unroll
            for (int i2 = 0; i2 < 2; ++i2) {
                int row = m0 + r + 32 * i2;
                float4 v = make_float4(0.f, 0.f, 0.f, 0.f);
                if (row < M) v = *(const float4*)(A + (size_t)row * 128 + kk + c);
                As[c + 0][r + 32 * i2] = v.x;
                As[c + 1][r + 32 * i2] = v.y;
                As[c + 2][r + 32 * i2] = v.z;
                As[c + 3][r + 32 * i2] = v.w;
            }
        }
        {   // W tile 32x64 fp32
            int r = t >> 4;
            int c = (t & 15) * 4;
#pragma unroll
            for (int i2 = 0; i2 < 2; ++i2) {
                int row = kk + r + 16 * i2;
                *(float4*)&Ws[r + 16 * i2][c] = *(const float4*)(W + (size_t)row * N + bn0 + c);
            }
        }
        __syncthreads();
#pragma unroll
        for (int k = 0; k < 32; ++k) {
            float4 a4 = *(const float4*)&As[k][4 * tm];
            float4 w4 = *(const float4*)&Ws[k][4 * tn];
            float av[4] = {a4.x, a4.y, a4.z, a4.w};
            float wv[4] = {w4.x, w4.y, w4.z, w4.w};
#pragma unroll
            for (int i = 0; i < 4; ++i)
#pragma unroll
                for (int j = 0; j < 4; ++j) acc[i][j] += av[i] * wv[j];
        }
        __syncthreads();
    }
#pragma unroll
    for (int i = 0; i < 4; ++i) {
        int row = m0 + 4 * tm + i;
        if (row < M) {
            float dvr = dinv[row];
            ushort4 v;
            v.x = f2bf(dvr * acc[i][0]); v.y = f2bf(dvr * acc[i][1]);
            v.z = f2bf(dvr * acc[i][2]); v.w = f2bf(dvr * acc[i][3]);
            *(ushort4*)(C + (size_t)row * N + bn0 + 4 * tn) = v;
        }
    }
}

// ---------------- CSR gather: pure row-sum of h', scale+bias at end ----------------
// out[d] = dinv[d] * (sum_in h'[src] + h'[d]) + b

// 128-wide bf16 rows (256 B): one wave per node, 4 B/lane; bf16 output (feeds GEMM2).
__global__ __launch_bounds__(256) void k_gather128(const int* __restrict__ rp,
                                                   const int* __restrict__ eperm,
                                                   const float* __restrict__ dinv,
                                                   const unsigned int* __restrict__ h,  // bf16x2
                                                   const float* __restrict__ bias,
                                                   unsigned int* __restrict__ out,      // bf16x2
                                                   int n) {
    int node = blockIdx.x * 4 + (threadIdx.x >> 6);
    if (node >= n) return;
    int lane = threadIdx.x & 63;
    int beg = rp[node], end = rp[node + 1];
    float2 acc = bf2_to_f2(h[(size_t)node * 64 + lane]);  // self h'[d]
    int j = beg;
    for (; j + 4 <= end; j += 4) {
        int e0 = eperm[j], e1 = eperm[j + 1], e2 = eperm[j + 2], e3 = eperm[j + 3];
        float2 v0 = bf2_to_f2(h[(size_t)e0 * 64 + lane]);
        float2 v1 = bf2_to_f2(h[(size_t)e1 * 64 + lane]);
        float2 v2 = bf2_to_f2(h[(size_t)e2 * 64 + lane]);
        float2 v3 = bf2_to_f2(h[(size_t)e3 * 64 + lane]);
        acc.x += (v0.x + v1.x) + (v2.x + v3.x);
        acc.y += (v0.y + v1.y) + (v2.y + v3.y);
    }
    for (; j < end; ++j) {
        float2 v = bf2_to_f2(h[(size_t)eperm[j] * 64 + lane]);
        acc.x += v.x;
        acc.y += v.y;
    }
    float dv = dinv[node];
    float2 bv = ((const float2*)bias)[lane];
    out[(size_t)node * 64 + lane] = pack_bf2(dv * acc.x + bv.x, dv * acc.y + bv.y);
}

// 64-wide bf16 rows (128 B): one wave per node; half-waves split the edge list,
// 4 B/lane; combine with shfl_xor(32). fp32 output (final).
__global__ __launch_bounds__(256) void k_gather64(const int* __restrict__ rp,
                                                  const int* __restrict__ eperm,
                                                  const float* __restrict__ dinv,
                                                  const unsigned int* __restrict__ h,  // bf16x2
                                                  const float* __restrict__ bias,
                                                  float* __restrict__ out, int n) {
    int node = blockIdx.x * 4 + (threadIdx.x >> 6);
    if (node >= n) return;
    int t = threadIdx.x;
    int l32 = t & 31;
    int half = (t >> 5) & 1;
    int beg = rp[node], end = rp[node + 1];
    float2 acc = make_float2(0.f, 0.f);
    if (half == 0) acc = bf2_to_f2(h[(size_t)node * 32 + l32]);  // self h'[d]
    int j = beg + half;
    for (; j + 6 < end; j += 8) {
        int e0 = eperm[j], e1 = eperm[j + 2], e2 = eperm[j + 4], e3 = eperm[j + 6];
        float2 v0 = bf2_to_f2(h[(size_t)e0 * 32 + l32]);
        float2 v1 = bf2_to_f2(h[(size_t)e1 * 32 + l32]);
        float2 v2 = bf2_to_f2(h[(size_t)e2 * 32 + l32]);
        float2 v3 = bf2_to_f2(h[(size_t)e3 * 32 + l32]);
        acc.x += (v0.x + v1.x) + (v2.x + v3.x);
        acc.y += (v0.y + v1.y) + (v2.y + v3.y);
    }
    for (; j < end; j += 2) {
        float2 v = bf2_to_f2(h[(size_t)eperm[j] * 32 + l32]);
        acc.x += v.x;
        acc.y += v.y;
    }
    acc.x += __shfl_xor(acc.x, 32);
    acc.y += __shfl_xor(acc.y, 32);
    if (half == 0) {
        float dv = dinv[node];
        float2 bv = ((const float2*)bias)[l32];
        ((float2*)out)[(size_t)node * 32 + l32] =
            make_float2(dv * acc.x + bv.x, dv * acc.y + bv.y);
    }
}

// ---------------- launch ----------------

extern "C" void kernel_launch(void* const* d_in, const int* in_sizes, int n_in,
                              void* d_out, int out_size, void* d_ws, size_t ws_size,
                              hipStream_t stream) {
    const float* x  = (const float*)d_in[0];
    const int*   ei = (const int*)d_in[1];
    const float* W1 = (const float*)d_in[2];
    const float* b1 = (const float*)d_in[3];
    const float* W2 = (const float*)d_in[4];
    const float* b2 = (const float*)d_in[5];
    float* out = (float*)d_out;

    const int N = in_sizes[0] / 128;
    const int E = in_sizes[1] / 2;
    const int* src = ei;
    const int* dst = ei + E;

    char* ws = (char*)d_ws;
    size_t off = 0;
    auto carve = [&](size_t bytes) -> void* {
        void* p = ws + off;
        off = (off + bytes + 255) & ~(size_t)255;
        return p;
    };
    float* dinv = (float*)carve((size_t)N * 4);
    int*   cnt  = (int*)carve((size_t)N * 4);
    int*   rp   = (int*)carve((size_t)(N + 1) * 4);
    int*   bsum = (int*)carve(128 * 4);
    int*   eperm = (int*)carve((size_t)E * 4);                        // src only
    unsigned short* h    = (unsigned short*)carve((size_t)N * 128 * 2);  // bf16 h' = dinv*(x@W1)
    unsigned short* hagg = (unsigned short*)carve((size_t)N * 128 * 2);  // bf16 layer-1 out (pre-relu)
    int* cursor = cnt;            // cnt dead after k_scan1
    unsigned short* h2 = h;       // h dead after k_gather128; h2' = dinv*(relu(hagg)@W2)

    const int gN  = (N + THREADS - 1) / THREADS;
    const int gN1 = (N + 1 + THREADS - 1) / THREADS;
    const int gE  = (E + THREADS - 1) / THREADS;
    const int gW  = (N + 3) / 4;
    const int gMm = (N + 63) / 64;
    const int nblk = (N + 1023) / 1024;  // <= 128

    // CSR build
    k_zero_i<<<gN, THREADS, 0, stream>>>(cnt, N);
    k_hist<<<gE, THREADS, 0, stream>>>(dst, cnt, E);
    k_scan1<<<nblk, 256, 0, stream>>>(cnt, rp, bsum, dinv, N);
    k_scan2<<<1, 128, 0, stream>>>(bsum, nblk);
    k_addoff<<<gN1, THREADS, 0, stream>>>(rp, bsum, cursor, N, E);
    k_permute<<<gE, THREADS, 0, stream>>>(src, dst, cursor, eperm, E);

    // layer 1
    k_gemm<false><<<dim3(gMm, 2), THREADS, 0, stream>>>(x, W1, dinv, h, N, 128);
    k_gather128<<<gW, THREADS, 0, stream>>>(rp, eperm, dinv, (const unsigned int*)h, b1,
                                            (unsigned int*)hagg, N);

    // layer 2
    k_gemm<true><<<dim3(gMm, 1), THREADS, 0, stream>>>(hagg, W2, dinv, h2, N, 64);
    k_gather64<<<gW, THREADS, 0, stream>>>(rp, eperm, dinv, (const unsigned int*)h2, b2, out, N);
}

// Round 5
// 367.244 us; speedup vs baseline: 1.3515x; 1.3515x over previous
//
#include <hip/hip_runtime.h>
#include <hip/hip_bf16.h>

#define THREADS 256
#define BSHIFT 9              // 512 nodes per coarse bucket; NB = ceil(N/512) <= 256
#define BIN_CHUNK 4096        // edges per k_bin block (16/thread)

// ---------------- helpers ----------------

__device__ inline unsigned short f2bf(float f) {  // round-to-nearest-even
    unsigned int u = __float_as_uint(f);
    unsigned int r = (u + 0x7fffu + ((u >> 16) & 1u)) >> 16;
    return (unsigned short)r;
}

__device__ inline unsigned int pack_bf2(float x, float y) {
    return (unsigned int)f2bf(x) | ((unsigned int)f2bf(y) << 16);
}

__device__ inline float2 bf2_to_f2(unsigned int u) {  // low bf16 -> x, high bf16 -> y
    float2 r;
    r.x = __uint_as_float(u << 16);
    r.y = __uint_as_float(u & 0xffff0000u);
    return r;
}

// ---------------- binned counting sort (no random global atomics) ----------------

__global__ void k_zero_i(int* p, int n) {
    int i = blockIdx.x * THREADS + threadIdx.x;
    if (i < n) p[i] = 0;
}

// coarse bucket totals: LDS histogram, 196 global adds per block
__global__ __launch_bounds__(256) void k_bcount(const int* __restrict__ dst,
                                                int* __restrict__ btot, int E, int NB) {
    __shared__ int c[256];
    int t = threadIdx.x;
    c[t] = 0;
    __syncthreads();
    for (int e = blockIdx.x * 256 + t; e < E; e += gridDim.x * 256)
        atomicAdd(&c[dst[e] >> BSHIFT], 1);
    __syncthreads();
    if (t < NB && c[t]) atomicAdd(&btot[t], c[t]);
}

// exclusive scan of bucket totals -> bstart[0..NB]; seed bcur
__global__ __launch_bounds__(256) void k_bscan(const int* __restrict__ btot,
                                               int* __restrict__ bstart,
                                               int* __restrict__ bcur, int NB, int E) {
    __shared__ int s[256];
    int t = threadIdx.x;
    int v = (t < NB) ? btot[t] : 0;
    s[t] = v;
    __syncthreads();
    for (int off = 1; off < 256; off <<= 1) {
        int add = (t >= off) ? s[t - off] : 0;
        __syncthreads();
        s[t] += add;
        __syncthreads();
    }
    int excl = s[t] - v;
    if (t < NB) {
        bstart[t] = excl;
        bcur[t] = excl;
    }
    if (t == 0) bstart[NB] = E;
}

// bin edges (src,dst) into coarse-bucket windows; one global atomic per bucket per block
__global__ __launch_bounds__(256) void k_bin(const int* __restrict__ src,
                                             const int* __restrict__ dst,
                                             int* __restrict__ bcur,
                                             int2* __restrict__ binned, int E, int NB) {
    __shared__ int bcnt[256];
    __shared__ int bres[256];
    int t = threadIdx.x;
    bcnt[t] = 0;
    __syncthreads();
    int base = blockIdx.x * BIN_CHUNK;
    int sv[16], dv[16];
#pragma unroll
    for (int i = 0; i < 16; ++i) {
        int e = base + t + i * 256;
        if (e < E) {
            sv[i] = src[e];
            dv[i] = dst[e];
            atomicAdd(&bcnt[dv[i] >> BSHIFT], 1);
        } else {
            dv[i] = -1;
        }
    }
    __syncthreads();
    if (t < NB) bres[t] = bcnt[t] ? atomicAdd(&bcur[t], bcnt[t]) : 0;
    __syncthreads();
#pragma unroll
    for (int i = 0; i < 16; ++i) {
        if (dv[i] >= 0) {
            int b = dv[i] >> BSHIFT;
            int pos = atomicAdd(&bres[b], 1);
            binned[pos] = make_int2(sv[i], dv[i]);
        }
    }
}

// per-bucket node histogram from binned data; coalesced cnt/dinv writes, no global atomics
__global__ __launch_bounds__(256) void k_node_count(const int2* __restrict__ binned,
                                                    const int* __restrict__ bstart,
                                                    int* __restrict__ cnt,
                                                    float* __restrict__ dinv, int N) {
    __shared__ int lc[512];
    int b = blockIdx.x;
    int t = threadIdx.x;
    for (int i = t; i < 512; i += 256) lc[i] = 0;
    __syncthreads();
    int beg = bstart[b], end = bstart[b + 1];
    int d0 = b << BSHIFT;
    for (int j = beg + t; j < end; j += 256) atomicAdd(&lc[binned[j].y - d0], 1);
    __syncthreads();
    for (int i = t; i < 512; i += 256) {
        int node = d0 + i;
        if (node < N) {
            cnt[node] = lc[i];
            dinv[node] = rsqrtf((float)lc[i] + 1.0f);  // +1 = self-loop
        }
    }
}

// per-block scan of 1024 ints (4/thread), exclusive within block; bsum gets block total
__global__ __launch_bounds__(256) void k_scan1(const int* __restrict__ cnt, int* __restrict__ part,
                                               int* __restrict__ bsum, int n) {
    __shared__ int s[256];
    int t = threadIdx.x;
    int base = blockIdx.x * 1024 + t * 4;
    int4 v = make_int4(0, 0, 0, 0);
    if (base + 3 < n) v = *(const int4*)(cnt + base);
    else {
        if (base < n) v.x = cnt[base];
        if (base + 1 < n) v.y = cnt[base + 1];
        if (base + 2 < n) v.z = cnt[base + 2];
        if (base + 3 < n) v.w = cnt[base + 3];
    }
    int mysum = v.x + v.y + v.z + v.w;
    s[t] = mysum;
    __syncthreads();
    for (int off = 1; off < 256; off <<= 1) {
        int add = (t >= off) ? s[t - off] : 0;
        __syncthreads();
        s[t] += add;
        __syncthreads();
    }
    int excl = s[t] - mysum;
    if (base < n) part[base] = excl;
    if (base + 1 < n) part[base + 1] = excl + v.x;
    if (base + 2 < n) part[base + 2] = excl + v.x + v.y;
    if (base + 3 < n) part[base + 3] = excl + v.x + v.y + v.z;
    if (t == 255) bsum[blockIdx.x] = s[255];
}

__global__ void k_scan2(int* bsum, int nblk) {
    __shared__ int s[128];
    int t = threadIdx.x;
    int v = (t < nblk) ? bsum[t] : 0;
    s[t] = v;
    __syncthreads();
    for (int off = 1; off < 128; off <<= 1) {
        int add = (t >= off) ? s[t - off] : 0;
        __syncthreads();
        s[t] += add;
        __syncthreads();
    }
    if (t < nblk) bsum[t] = s[t] - v;  // exclusive
}

__global__ void k_addoff(int* __restrict__ rp, const int* __restrict__ bsum, int n, int E) {
    int i = blockIdx.x * THREADS + threadIdx.x;
    if (i < n) rp[i] += bsum[i >> 10];
    else if (i == n) rp[n] = E;
}

// per-bucket final placement: LDS cursors seeded from rp window; writes confined to
// the bucket's contiguous eperm window (~32 KB) -> L2-hot, full-line evictions
__global__ __launch_bounds__(256) void k_place(const int2* __restrict__ binned,
                                               const int* __restrict__ bstart,
                                               const int* __restrict__ rp,
                                               int* __restrict__ eperm, int N) {
    __shared__ int lcur[512];
    int b = blockIdx.x;
    int t = threadIdx.x;
    int d0 = b << BSHIFT;
    for (int i = t; i < 512; i += 256) {
        int node = d0 + i;
        lcur[i] = (node < N) ? rp[node] : 0;
    }
    __syncthreads();
    int beg = bstart[b], end = bstart[b + 1];
    for (int j = beg + t; j < end; j += 256) {
        int2 e = binned[j];
        int pos = atomicAdd(&lcur[e.y - d0], 1);
        eperm[pos] = e.x;
    }
}

// ---------------- GEMM: C[M x N](bf16) = dinv[row] * (A[M x 128] @ W[128 x N]) --------
// ABF16_RELU: A is bf16 and relu is applied on load (layer 2). Else A fp32 (layer 1).

template <bool ABF16_RELU>
__global__ __launch_bounds__(256) void k_gemm(const void* __restrict__ Av,
                                              const float* __restrict__ W,
                                              const float* __restrict__ dinv,
                                              unsigned short* __restrict__ C, int M, int N) {
    __shared__ float As[32][68];
    __shared__ float Ws[32][68];
    const int t = threadIdx.x;
    const int m0 = blockIdx.x * 64;
    const int bn0 = blockIdx.y * 64;
    const int tm = t & 15;
    const int tn = t >> 4;
    float acc[4][4] = {};

    for (int kk = 0; kk < 128; kk += 32) {
        if (ABF16_RELU) {   // A tile 64x32 bf16 -> relu -> transposed
            const unsigned short* A = (const unsigned short*)Av;
            int r = t >> 2;            // 0..63
            int c = (t & 3) * 8;       // 0,8,16,24
            int row = m0 + r;
            uint4 u = make_uint4(0, 0, 0, 0);
            if (row < M) u = *(const uint4*)(A + (size_t)row * 128 + kk + c);
            float2 f0 = bf2_to_f2(u.x), f1 = bf2_to_f2(u.y);
            float2 f2v = bf2_to_f2(u.z), f3 = bf2_to_f2(u.w);
            As[c + 0][r] = fmaxf(f0.x, 0.f);
            As[c + 1][r] = fmaxf(f0.y, 0.f);
            As[c + 2][r] = fmaxf(f1.x, 0.f);
            As[c + 3][r] = fmaxf(f1.y, 0.f);
            As[c + 4][r] = fmaxf(f2v.x, 0.f);
            As[c + 5][r] = fmaxf(f2v.y, 0.f);
            As[c + 6][r] = fmaxf(f3.x, 0.f);
            As[c + 7][r] = fmaxf(f3.y, 0.f);
        } else {            // A tile 64x32 fp32 -> transposed
            const float* A = (const float*)Av;
            int r = t >> 3;            // 0..31
            int c = (t & 7) * 4;       // 0,4,..,28
#pragma unroll
            for (int i2 = 0; i2 < 2; ++i2) {
                int row = m0 + r + 32 * i2;
                float4 v = make_float4(0.f, 0.f, 0.f, 0.f);
                if (row < M) v = *(const float4*)(A + (size_t)row * 128 + kk + c);
                As[c + 0][r + 32 * i2] = v.x;
                As[c + 1][r + 32 * i2] = v.y;
                As[c + 2][r + 32 * i2] = v.z;
                As[c + 3][r + 32 * i2] = v.w;
            }
        }
        {   // W tile 32x64 fp32
            int r = t >> 4;
            int c = (t & 15) * 4;
#pragma unroll
            for (int i2 = 0; i2 < 2; ++i2) {
                int row = kk + r + 16 * i2;
                *(float4*)&Ws[r + 16 * i2][c] = *(const float4*)(W + (size_t)row * N + bn0 + c);
            }
        }
        __syncthreads();
#pragma unroll
        for (int k = 0; k < 32; ++k) {
            float4 a4 = *(const float4*)&As[k][4 * tm];
            float4 w4 = *(const float4*)&Ws[k][4 * tn];
            float av[4] = {a4.x, a4.y, a4.z, a4.w};
            float wv[4] = {w4.x, w4.y, w4.z, w4.w};
#pragma unroll
            for (int i = 0; i < 4; ++i)
#pragma unroll
                for (int j = 0; j < 4; ++j) acc[i][j] += av[i] * wv[j];
        }
        __syncthreads();
    }
#pragma unroll
    for (int i = 0; i < 4; ++i) {
        int row = m0 + 4 * tm + i;
        if (row < M) {
            float dvr = dinv[row];
            ushort4 v;
            v.x = f2bf(dvr * acc[i][0]); v.y = f2bf(dvr * acc[i][1]);
            v.z = f2bf(dvr * acc[i][2]); v.w = f2bf(dvr * acc[i][3]);
            *(ushort4*)(C + (size_t)row * N + bn0 + 4 * tn) = v;
        }
    }
}

// ---------------- CSR gather: out[d] = dinv[d] * (sum_in h'[src] + h'[d]) + b --------

// 128-wide bf16 rows (256 B): one wave per node, 4 B/lane; bf16 output (feeds GEMM2).
__global__ __launch_bounds__(256) void k_gather128(const int* __restrict__ rp,
                                                   const int* __restrict__ eperm,
                                                   const float* __restrict__ dinv,
                                                   const unsigned int* __restrict__ h,  // bf16x2
                                                   const float* __restrict__ bias,
                                                   unsigned int* __restrict__ out,      // bf16x2
                                                   int n) {
    int node = blockIdx.x * 4 + (threadIdx.x >> 6);
    if (node >= n) return;
    int lane = threadIdx.x & 63;
    int beg = rp[node], end = rp[node + 1];
    float2 acc = bf2_to_f2(h[(size_t)node * 64 + lane]);  // self h'[d]
    int j = beg;
    for (; j + 4 <= end; j += 4) {
        int e0 = eperm[j], e1 = eperm[j + 1], e2 = eperm[j + 2], e3 = eperm[j + 3];
        float2 v0 = bf2_to_f2(h[(size_t)e0 * 64 + lane]);
        float2 v1 = bf2_to_f2(h[(size_t)e1 * 64 + lane]);
        float2 v2 = bf2_to_f2(h[(size_t)e2 * 64 + lane]);
        float2 v3 = bf2_to_f2(h[(size_t)e3 * 64 + lane]);
        acc.x += (v0.x + v1.x) + (v2.x + v3.x);
        acc.y += (v0.y + v1.y) + (v2.y + v3.y);
    }
    for (; j < end; ++j) {
        float2 v = bf2_to_f2(h[(size_t)eperm[j] * 64 + lane]);
        acc.x += v.x;
        acc.y += v.y;
    }
    float dv = dinv[node];
    float2 bv = ((const float2*)bias)[lane];
    out[(size_t)node * 64 + lane] = pack_bf2(dv * acc.x + bv.x, dv * acc.y + bv.y);
}

// 64-wide bf16 rows (128 B): one wave per node; half-waves split the edge list,
// 4 B/lane; combine with shfl_xor(32). fp32 output (final).
__global__ __launch_bounds__(256) void k_gather64(const int* __restrict__ rp,
                                                  const int* __restrict__ eperm,
                                                  const float* __restrict__ dinv,
                                                  const unsigned int* __restrict__ h,  // bf16x2
                                                  const float* __restrict__ bias,
                                                  float* __restrict__ out, int n) {
    int node = blockIdx.x * 4 + (threadIdx.x >> 6);
    if (node >= n) return;
    int t = threadIdx.x;
    int l32 = t & 31;
    int half = (t >> 5) & 1;
    int beg = rp[node], end = rp[node + 1];
    float2 acc = make_float2(0.f, 0.f);
    if (half == 0) acc = bf2_to_f2(h[(size_t)node * 32 + l32]);  // self h'[d]
    int j = beg + half;
    for (; j + 6 < end; j += 8) {
        int e0 = eperm[j], e1 = eperm[j + 2], e2 = eperm[j + 4], e3 = eperm[j + 6];
        float2 v0 = bf2_to_f2(h[(size_t)e0 * 32 + l32]);
        float2 v1 = bf2_to_f2(h[(size_t)e1 * 32 + l32]);
        float2 v2 = bf2_to_f2(h[(size_t)e2 * 32 + l32]);
        float2 v3 = bf2_to_f2(h[(size_t)e3 * 32 + l32]);
        acc.x += (v0.x + v1.x) + (v2.x + v3.x);
        acc.y += (v0.y + v1.y) + (v2.y + v3.y);
    }
    for (; j < end; j += 2) {
        float2 v = bf2_to_f2(h[(size_t)eperm[j] * 32 + l32]);
        acc.x += v.x;
        acc.y += v.y;
    }
    acc.x += __shfl_xor(acc.x, 32);
    acc.y += __shfl_xor(acc.y, 32);
    if (half == 0) {
        float dv = dinv[node];
        float2 bv = ((const float2*)bias)[l32];
        ((float2*)out)[(size_t)node * 32 + l32] =
            make_float2(dv * acc.x + bv.x, dv * acc.y + bv.y);
    }
}

// ---------------- launch ----------------

extern "C" void kernel_launch(void* const* d_in, const int* in_sizes, int n_in,
                              void* d_out, int out_size, void* d_ws, size_t ws_size,
                              hipStream_t stream) {
    const float* x  = (const float*)d_in[0];
    const int*   ei = (const int*)d_in[1];
    const float* W1 = (const float*)d_in[2];
    const float* b1 = (const float*)d_in[3];
    const float* W2 = (const float*)d_in[4];
    const float* b2 = (const float*)d_in[5];
    float* out = (float*)d_out;

    const int N = in_sizes[0] / 128;
    const int E = in_sizes[1] / 2;
    const int* src = ei;
    const int* dst = ei + E;
    const int NB = (N + 511) >> BSHIFT;  // coarse buckets (<= 256 for N <= 131072)

    char* ws = (char*)d_ws;
    size_t off = 0;
    auto carve = [&](size_t bytes) -> void* {
        void* p = ws + off;
        off = (off + bytes + 255) & ~(size_t)255;
        return p;
    };
    float* dinv = (float*)carve((size_t)N * 4);
    int*   cnt  = (int*)carve((size_t)N * 4);
    int*   rp   = (int*)carve((size_t)(N + 1) * 4);
    int*   bsum = (int*)carve(128 * 4);
    int*   btot = (int*)carve(256 * 4);
    int*   bstart = (int*)carve(257 * 4);
    int*   bcur = (int*)carve(256 * 4);
    int2*  binned = (int2*)carve((size_t)E * 8);     // (src,dst) bucket-grouped
    int*   eperm  = (int*)carve((size_t)E * 4);      // src, dst-sorted
    unsigned short* h    = (unsigned short*)carve((size_t)N * 128 * 2);  // bf16 h' = dinv*(x@W1)
    unsigned short* hagg = (unsigned short*)carve((size_t)N * 128 * 2);  // bf16 layer-1 out
    unsigned short* h2 = h;  // h dead after gather128

    const int gN1 = (N + 1 + THREADS - 1) / THREADS;
    const int gW  = (N + 3) / 4;
    const int gMm = (N + 63) / 64;
    const int nblk = (N + 1023) / 1024;  // <= 128

    // ---- binned counting sort (CSR build) ----
    k_zero_i<<<1, THREADS, 0, stream>>>(btot, 256);
    k_bcount<<<512, THREADS, 0, stream>>>(dst, btot, E, NB);
    k_bscan<<<1, THREADS, 0, stream>>>(btot, bstart, bcur, NB, E);
    k_bin<<<(E + BIN_CHUNK - 1) / BIN_CHUNK, THREADS, 0, stream>>>(src, dst, bcur, binned, E, NB);
    k_node_count<<<NB, THREADS, 0, stream>>>(binned, bstart, cnt, dinv, N);
    k_scan1<<<nblk, 256, 0, stream>>>(cnt, rp, bsum, N);
    k_scan2<<<1, 128, 0, stream>>>(bsum, nblk);
    k_addoff<<<gN1, THREADS, 0, stream>>>(rp, bsum, N, E);
    k_place<<<NB, THREADS, 0, stream>>>(binned, bstart, rp, eperm, N);

    // ---- layer 1 ----
    k_gemm<false><<<dim3(gMm, 2), THREADS, 0, stream>>>(x, W1, dinv, h, N, 128);
    k_gather128<<<gW, THREADS, 0, stream>>>(rp, eperm, dinv, (const unsigned int*)h, b1,
                                            (unsigned int*)hagg, N);

    // ---- layer 2 ----
    k_gemm<true><<<dim3(gMm, 1), THREADS, 0, stream>>>(hagg, W2, dinv, h2, N, 64);
    k_gather64<<<gW, THREADS, 0, stream>>>(rp, eperm, dinv, (const unsigned int*)h2, b2, out, N);
}

// Round 6
// 354.390 us; speedup vs baseline: 1.4005x; 1.0363x over previous
//
#include <hip/hip_runtime.h>
#include <hip/hip_bf16.h>

#define THREADS 256
#define BSHIFT 9              // 512 nodes per coarse bucket; NB = ceil(N/512) <= 256
#define BIN_CHUNK 4096        // edges per k_bin block (16/thread)

typedef __attribute__((ext_vector_type(8))) short bf16x8;
typedef __attribute__((ext_vector_type(4))) float f32x4;

// ---------------- helpers ----------------

__device__ inline unsigned short f2bf(float f) {  // round-to-nearest-even
    unsigned int u = __float_as_uint(f);
    unsigned int r = (u + 0x7fffu + ((u >> 16) & 1u)) >> 16;
    return (unsigned short)r;
}

__device__ inline unsigned int pack_bf2(float x, float y) {
    return (unsigned int)f2bf(x) | ((unsigned int)f2bf(y) << 16);
}

__device__ inline float2 bf2_to_f2(unsigned int u) {  // low bf16 -> x, high bf16 -> y
    float2 r;
    r.x = __uint_as_float(u << 16);
    r.y = __uint_as_float(u & 0xffff0000u);
    return r;
}

__device__ inline unsigned short bf_relu(unsigned short v) {
    return (v & 0x8000u) ? (unsigned short)0 : v;
}

// ---------------- binned counting sort (no random global atomics) ----------------

__global__ void k_zero_i(int* p, int n) {
    int i = blockIdx.x * THREADS + threadIdx.x;
    if (i < n) p[i] = 0;
}

__global__ __launch_bounds__(256) void k_bcount(const int* __restrict__ dst,
                                                int* __restrict__ btot, int E, int NB) {
    __shared__ int c[256];
    int t = threadIdx.x;
    c[t] = 0;
    __syncthreads();
    for (int e = blockIdx.x * 256 + t; e < E; e += gridDim.x * 256)
        atomicAdd(&c[dst[e] >> BSHIFT], 1);
    __syncthreads();
    if (t < NB && c[t]) atomicAdd(&btot[t], c[t]);
}

__global__ __launch_bounds__(256) void k_bscan(const int* __restrict__ btot,
                                               int* __restrict__ bstart,
                                               int* __restrict__ bcur, int NB, int E) {
    __shared__ int s[256];
    int t = threadIdx.x;
    int v = (t < NB) ? btot[t] : 0;
    s[t] = v;
    __syncthreads();
    for (int off = 1; off < 256; off <<= 1) {
        int add = (t >= off) ? s[t - off] : 0;
        __syncthreads();
        s[t] += add;
        __syncthreads();
    }
    int excl = s[t] - v;
    if (t < NB) {
        bstart[t] = excl;
        bcur[t] = excl;
    }
    if (t == 0) bstart[NB] = E;
}

__global__ __launch_bounds__(256) void k_bin(const int* __restrict__ src,
                                             const int* __restrict__ dst,
                                             int* __restrict__ bcur,
                                             int2* __restrict__ binned, int E, int NB) {
    __shared__ int bcnt[256];
    __shared__ int bres[256];
    int t = threadIdx.x;
    bcnt[t] = 0;
    __syncthreads();
    int base = blockIdx.x * BIN_CHUNK;
    int sv[16], dv[16];
#pragma unroll
    for (int i = 0; i < 16; ++i) {
        int e = base + t + i * 256;
        if (e < E) {
            sv[i] = src[e];
            dv[i] = dst[e];
            atomicAdd(&bcnt[dv[i] >> BSHIFT], 1);
        } else {
            dv[i] = -1;
        }
    }
    __syncthreads();
    if (t < NB) bres[t] = bcnt[t] ? atomicAdd(&bcur[t], bcnt[t]) : 0;
    __syncthreads();
#pragma unroll
    for (int i = 0; i < 16; ++i) {
        if (dv[i] >= 0) {
            int b = dv[i] >> BSHIFT;
            int pos = atomicAdd(&bres[b], 1);
            binned[pos] = make_int2(sv[i], dv[i]);
        }
    }
}

__global__ __launch_bounds__(256) void k_node_count(const int2* __restrict__ binned,
                                                    const int* __restrict__ bstart,
                                                    int* __restrict__ cnt,
                                                    float* __restrict__ dinv, int N) {
    __shared__ int lc[512];
    int b = blockIdx.x;
    int t = threadIdx.x;
    for (int i = t; i < 512; i += 256) lc[i] = 0;
    __syncthreads();
    int beg = bstart[b], end = bstart[b + 1];
    int d0 = b << BSHIFT;
    for (int j = beg + t; j < end; j += 256) atomicAdd(&lc[binned[j].y - d0], 1);
    __syncthreads();
    for (int i = t; i < 512; i += 256) {
        int node = d0 + i;
        if (node < N) {
            cnt[node] = lc[i];
            dinv[node] = rsqrtf((float)lc[i] + 1.0f);  // +1 = self-loop
        }
    }
}

__global__ __launch_bounds__(256) void k_scan1(const int* __restrict__ cnt, int* __restrict__ part,
                                               int* __restrict__ bsum, int n) {
    __shared__ int s[256];
    int t = threadIdx.x;
    int base = blockIdx.x * 1024 + t * 4;
    int4 v = make_int4(0, 0, 0, 0);
    if (base + 3 < n) v = *(const int4*)(cnt + base);
    else {
        if (base < n) v.x = cnt[base];
        if (base + 1 < n) v.y = cnt[base + 1];
        if (base + 2 < n) v.z = cnt[base + 2];
        if (base + 3 < n) v.w = cnt[base + 3];
    }
    int mysum = v.x + v.y + v.z + v.w;
    s[t] = mysum;
    __syncthreads();
    for (int off = 1; off < 256; off <<= 1) {
        int add = (t >= off) ? s[t - off] : 0;
        __syncthreads();
        s[t] += add;
        __syncthreads();
    }
    int excl = s[t] - mysum;
    if (base < n) part[base] = excl;
    if (base + 1 < n) part[base + 1] = excl + v.x;
    if (base + 2 < n) part[base + 2] = excl + v.x + v.y;
    if (base + 3 < n) part[base + 3] = excl + v.x + v.y + v.z;
    if (t == 255) bsum[blockIdx.x] = s[255];
}

__global__ void k_scan2(int* bsum, int nblk) {
    __shared__ int s[128];
    int t = threadIdx.x;
    int v = (t < nblk) ? bsum[t] : 0;
    s[t] = v;
    __syncthreads();
    for (int off = 1; off < 128; off <<= 1) {
        int add = (t >= off) ? s[t - off] : 0;
        __syncthreads();
        s[t] += add;
        __syncthreads();
    }
    if (t < nblk) bsum[t] = s[t] - v;  // exclusive
}

__global__ void k_addoff(int* __restrict__ rp, const int* __restrict__ bsum, int n, int E) {
    int i = blockIdx.x * THREADS + threadIdx.x;
    if (i < n) rp[i] += bsum[i >> 10];
    else if (i == n) rp[n] = E;
}

__global__ __launch_bounds__(256) void k_place(const int2* __restrict__ binned,
                                               const int* __restrict__ bstart,
                                               const int* __restrict__ rp,
                                               int* __restrict__ eperm, int N) {
    __shared__ int lcur[512];
    int b = blockIdx.x;
    int t = threadIdx.x;
    int d0 = b << BSHIFT;
    for (int i = t; i < 512; i += 256) {
        int node = d0 + i;
        lcur[i] = (node < N) ? rp[node] : 0;
    }
    __syncthreads();
    int beg = bstart[b], end = bstart[b + 1];
    for (int j = beg + t; j < end; j += 256) {
        int2 e = binned[j];
        int pos = atomicAdd(&lcur[e.y - d0], 1);
        eperm[pos] = e.x;
    }
}

// ---------------- MFMA GEMM: C[M x N](bf16) = dinv[row] * (A[M x 128] @ W[128 x N]) ----
// Block = 4 waves, M-tile 64, full K=128 staged in LDS. Each wave: 4 m-tiles x NT n-tiles,
// NT = N/64 (wave covers 16*NT cols). Fragment layouts (m89/m120-verified):
//   A[m = lane&15][k = (lane>>4)*8 + j],  B[k = (lane>>4)*8 + j][n = lane&15]
//   C/D: row = (lane>>4)*4 + reg, col = lane&15.
// ABF16_RELU: A is bf16 with relu on load (layer 2); else A fp32 (layer 1).

template <int N, bool ABF16_RELU>
__global__ __launch_bounds__(256) void k_gemm_mfma(const void* __restrict__ Av,
                                                   const float* __restrict__ W,
                                                   const float* __restrict__ dinv,
                                                   unsigned short* __restrict__ C, int M) {
    static_assert(N == 64 || N == 128, "N must be 64 or 128");
    constexpr int NT = N / 64;          // n-tiles per wave
    constexpr int KP = 136;             // padded K stride (bf16 elems), 272 B rows
    __shared__ short As[64 * KP];       // A tile [m][k]
    __shared__ short Bs[N * KP];        // B transposed [n][k]
    __shared__ float sDin[64];

    const int t = threadIdx.x;
    const int m0 = blockIdx.x * 64;

    // ---- stage A (64 rows x 128 k), convert to bf16 ----
    {
        int ar = t >> 5;            // 0..7
        int ac = (t & 31) * 4;      // 0..124
#pragma unroll
        for (int rb = 0; rb < 64; rb += 8) {
            int lrow = rb + ar;
            int row = m0 + lrow;
            ushort4 sv = make_ushort4(0, 0, 0, 0);
            if (ABF16_RELU) {
                if (row < M) {
                    ushort4 u = *(const ushort4*)((const unsigned short*)Av + (size_t)row * 128 + ac);
                    sv.x = bf_relu(u.x); sv.y = bf_relu(u.y);
                    sv.z = bf_relu(u.z); sv.w = bf_relu(u.w);
                }
            } else {
                if (row < M) {
                    float4 v = *(const float4*)((const float*)Av + (size_t)row * 128 + ac);
                    sv.x = f2bf(v.x); sv.y = f2bf(v.y); sv.z = f2bf(v.z); sv.w = f2bf(v.w);
                }
            }
            *(ushort4*)&As[lrow * KP + ac] = sv;
        }
    }
    // ---- stage B transposed: Bs[n][k] <- W[k][n] (fp32 -> bf16) ----
    {
        constexpr int TPR = N / 4;       // threads per k-row
        constexpr int KPI = 256 / TPR;   // k-rows per iteration
        int bk = t / TPR;
        int bn = (t % TPR) * 4;
#pragma unroll
        for (int kb = 0; kb < 128; kb += KPI) {
            int k = kb + bk;
            float4 wv = *(const float4*)(W + (size_t)k * N + bn);
            Bs[(bn + 0) * KP + k] = f2bf(wv.x);
            Bs[(bn + 1) * KP + k] = f2bf(wv.y);
            Bs[(bn + 2) * KP + k] = f2bf(wv.z);
            Bs[(bn + 3) * KP + k] = f2bf(wv.w);
        }
    }
    if (t < 64) sDin[t] = (m0 + t < M) ? dinv[m0 + t] : 1.0f;
    __syncthreads();

    // ---- compute ----
    const int w = t >> 6;
    const int lane = t & 63;
    const int lm = lane & 15;
    const int qd = lane >> 4;
    const int n0w = w * 16 * NT;

    f32x4 acc[4][NT];
#pragma unroll
    for (int mi = 0; mi < 4; ++mi)
#pragma unroll
        for (int ni = 0; ni < NT; ++ni) acc[mi][ni] = (f32x4){0.f, 0.f, 0.f, 0.f};

#pragma unroll
    for (int ks = 0; ks < 4; ++ks) {
        bf16x8 a[4], b[NT];
#pragma unroll
        for (int mi = 0; mi < 4; ++mi)
            a[mi] = *(const bf16x8*)&As[(mi * 16 + lm) * KP + ks * 32 + qd * 8];
#pragma unroll
        for (int ni = 0; ni < NT; ++ni)
            b[ni] = *(const bf16x8*)&Bs[(n0w + ni * 16 + lm) * KP + ks * 32 + qd * 8];
#pragma unroll
        for (int mi = 0; mi < 4; ++mi)
#pragma unroll
            for (int ni = 0; ni < NT; ++ni)
                acc[mi][ni] = __builtin_amdgcn_mfma_f32_16x16x32_bf16(a[mi], b[ni], acc[mi][ni], 0, 0, 0);
    }

    // ---- epilogue: scale by dinv, store bf16 ----
#pragma unroll
    for (int mi = 0; mi < 4; ++mi) {
#pragma unroll
        for (int ni = 0; ni < NT; ++ni) {
            int col = n0w + ni * 16 + lm;
#pragma unroll
            for (int r = 0; r < 4; ++r) {
                int lrow = mi * 16 + qd * 4 + r;
                int row = m0 + lrow;
                if (row < M) C[(size_t)row * N + col] = f2bf(sDin[lrow] * acc[mi][ni][r]);
            }
        }
    }
}

// ---------------- CSR gather: out[d] = dinv[d] * (sum_in h'[src] + h'[d]) + b --------

__global__ __launch_bounds__(256) void k_gather128(const int* __restrict__ rp,
                                                   const int* __restrict__ eperm,
                                                   const float* __restrict__ dinv,
                                                   const unsigned int* __restrict__ h,  // bf16x2
                                                   const float* __restrict__ bias,
                                                   unsigned int* __restrict__ out,      // bf16x2
                                                   int n) {
    int node = blockIdx.x * 4 + (threadIdx.x >> 6);
    if (node >= n) return;
    int lane = threadIdx.x & 63;
    int beg = rp[node], end = rp[node + 1];
    float2 acc = bf2_to_f2(h[(size_t)node * 64 + lane]);  // self h'[d]
    int j = beg;
    for (; j + 4 <= end; j += 4) {
        int e0 = eperm[j], e1 = eperm[j + 1], e2 = eperm[j + 2], e3 = eperm[j + 3];
        float2 v0 = bf2_to_f2(h[(size_t)e0 * 64 + lane]);
        float2 v1 = bf2_to_f2(h[(size_t)e1 * 64 + lane]);
        float2 v2 = bf2_to_f2(h[(size_t)e2 * 64 + lane]);
        float2 v3 = bf2_to_f2(h[(size_t)e3 * 64 + lane]);
        acc.x += (v0.x + v1.x) + (v2.x + v3.x);
        acc.y += (v0.y + v1.y) + (v2.y + v3.y);
    }
    for (; j < end; ++j) {
        float2 v = bf2_to_f2(h[(size_t)eperm[j] * 64 + lane]);
        acc.x += v.x;
        acc.y += v.y;
    }
    float dv = dinv[node];
    float2 bv = ((const float2*)bias)[lane];
    out[(size_t)node * 64 + lane] = pack_bf2(dv * acc.x + bv.x, dv * acc.y + bv.y);
}

__global__ __launch_bounds__(256) void k_gather64(const int* __restrict__ rp,
                                                  const int* __restrict__ eperm,
                                                  const float* __restrict__ dinv,
                                                  const unsigned int* __restrict__ h,  // bf16x2
                                                  const float* __restrict__ bias,
                                                  float* __restrict__ out, int n) {
    int node = blockIdx.x * 4 + (threadIdx.x >> 6);
    if (node >= n) return;
    int t = threadIdx.x;
    int l32 = t & 31;
    int half = (t >> 5) & 1;
    int beg = rp[node], end = rp[node + 1];
    float2 acc = make_float2(0.f, 0.f);
    if (half == 0) acc = bf2_to_f2(h[(size_t)node * 32 + l32]);  // self h'[d]
    int j = beg + half;
    for (; j + 6 < end; j += 8) {
        int e0 = eperm[j], e1 = eperm[j + 2], e2 = eperm[j + 4], e3 = eperm[j + 6];
        float2 v0 = bf2_to_f2(h[(size_t)e0 * 32 + l32]);
        float2 v1 = bf2_to_f2(h[(size_t)e1 * 32 + l32]);
        float2 v2 = bf2_to_f2(h[(size_t)e2 * 32 + l32]);
        float2 v3 = bf2_to_f2(h[(size_t)e3 * 32 + l32]);
        acc.x += (v0.x + v1.x) + (v2.x + v3.x);
        acc.y += (v0.y + v1.y) + (v2.y + v3.y);
    }
    for (; j < end; j += 2) {
        float2 v = bf2_to_f2(h[(size_t)eperm[j] * 32 + l32]);
        acc.x += v.x;
        acc.y += v.y;
    }
    acc.x += __shfl_xor(acc.x, 32);
    acc.y += __shfl_xor(acc.y, 32);
    if (half == 0) {
        float dv = dinv[node];
        float2 bv = ((const float2*)bias)[l32];
        ((float2*)out)[(size_t)node * 32 + l32] =
            make_float2(dv * acc.x + bv.x, dv * acc.y + bv.y);
    }
}

// ---------------- launch ----------------

extern "C" void kernel_launch(void* const* d_in, const int* in_sizes, int n_in,
                              void* d_out, int out_size, void* d_ws, size_t ws_size,
                              hipStream_t stream) {
    const float* x  = (const float*)d_in[0];
    const int*   ei = (const int*)d_in[1];
    const float* W1 = (const float*)d_in[2];
    const float* b1 = (const float*)d_in[3];
    const float* W2 = (const float*)d_in[4];
    const float* b2 = (const float*)d_in[5];
    float* out = (float*)d_out;

    const int N = in_sizes[0] / 128;
    const int E = in_sizes[1] / 2;
    const int* src = ei;
    const int* dst = ei + E;
    const int NB = (N + 511) >> BSHIFT;  // coarse buckets (<= 256 for N <= 131072)

    char* ws = (char*)d_ws;
    size_t off = 0;
    auto carve = [&](size_t bytes) -> void* {
        void* p = ws + off;
        off = (off + bytes + 255) & ~(size_t)255;
        return p;
    };
    float* dinv = (float*)carve((size_t)N * 4);
    int*   cnt  = (int*)carve((size_t)N * 4);
    int*   rp   = (int*)carve((size_t)(N + 1) * 4);
    int*   bsum = (int*)carve(128 * 4);
    int*   btot = (int*)carve(256 * 4);
    int*   bstart = (int*)carve(257 * 4);
    int*   bcur = (int*)carve(256 * 4);
    int2*  binned = (int2*)carve((size_t)E * 8);     // (src,dst) bucket-grouped
    int*   eperm  = (int*)carve((size_t)E * 4);      // src, dst-sorted
    unsigned short* h    = (unsigned short*)carve((size_t)N * 128 * 2);  // bf16 h' = dinv*(x@W1)
    unsigned short* hagg = (unsigned short*)carve((size_t)N * 128 * 2);  // bf16 layer-1 out
    unsigned short* h2 = h;  // h dead after gather128

    const int gN1 = (N + 1 + THREADS - 1) / THREADS;
    const int gW  = (N + 3) / 4;
    const int gMm = (N + 63) / 64;
    const int nblk = (N + 1023) / 1024;  // <= 128

    // ---- binned counting sort (CSR build) ----
    k_zero_i<<<1, THREADS, 0, stream>>>(btot, 256);
    k_bcount<<<512, THREADS, 0, stream>>>(dst, btot, E, NB);
    k_bscan<<<1, THREADS, 0, stream>>>(btot, bstart, bcur, NB, E);
    k_bin<<<(E + BIN_CHUNK - 1) / BIN_CHUNK, THREADS, 0, stream>>>(src, dst, bcur, binned, E, NB);
    k_node_count<<<NB, THREADS, 0, stream>>>(binned, bstart, cnt, dinv, N);
    k_scan1<<<nblk, 256, 0, stream>>>(cnt, rp, bsum, N);
    k_scan2<<<1, 128, 0, stream>>>(bsum, nblk);
    k_addoff<<<gN1, THREADS, 0, stream>>>(rp, bsum, N, E);
    k_place<<<NB, THREADS, 0, stream>>>(binned, bstart, rp, eperm, N);

    // ---- layer 1 ----
    k_gemm_mfma<128, false><<<gMm, THREADS, 0, stream>>>(x, W1, dinv, h, N);
    k_gather128<<<gW, THREADS, 0, stream>>>(rp, eperm, dinv, (const unsigned int*)h, b1,
                                            (unsigned int*)hagg, N);

    // ---- layer 2 ----
    k_gemm_mfma<64, true><<<gMm, THREADS, 0, stream>>>(hagg, W2, dinv, h2, N);
    k_gather64<<<gW, THREADS, 0, stream>>>(rp, eperm, dinv, (const unsigned int*)h2, b2, out, N);
}